// Round 3
// baseline (2956.554 us; speedup 1.0000x reference)
//
#include <hip/hip_runtime.h>
#include <hip/hip_fp16.h>

#define B 32
#define R 2048
#define C 32
#define O 32
#define IN 16
#define RO (O * IN)  // 512 elems per (r,c) row-slice

// K0: vote_h[c][r][o][i] = (half) vote[r][c][o][i]   (transpose r<->c, fp32->fp16)
// Flat: each thread converts 8 consecutive input floats; writes 16B chunks,
// contiguous 1KB runs per (r,c).
__global__ __launch_bounds__(256) void convert_kernel(
    const float* __restrict__ vote,   // [R][C][O][IN]
    __half* __restrict__ vote_h)      // [C][R][O][IN]
{
  int g = blockIdx.x * 256 + threadIdx.x;  // 0 .. R*C*64-1
  int e8 = g & 63;   // 8-elem chunk within the 512-elem (r,c) slice
  int rc = g >> 6;
  int r = rc >> 5;
  int c = rc & 31;
  const float4* in4 = reinterpret_cast<const float4*>(vote + (size_t)g * 8);
  float4 A = in4[0], Bv = in4[1];
  __half tmp[8];
  tmp[0] = __float2half(A.x);  tmp[1] = __float2half(A.y);
  tmp[2] = __float2half(A.z);  tmp[3] = __float2half(A.w);
  tmp[4] = __float2half(Bv.x); tmp[5] = __float2half(Bv.y);
  tmp[6] = __float2half(Bv.z); tmp[7] = __float2half(Bv.w);
  uint4 w = *reinterpret_cast<uint4*>(tmp);
  *reinterpret_cast<uint4*>(vote_h + ((size_t)c * R + r) * RO + e8 * 8) = w;
}

// Fused: one block per (b,c). Thread t computes votes rows r=t and r=t+1024
// from vote_h (fp16) and x (fp32) directly into registers, then runs all 3
// routing iterations in-block. XCD swizzle: blocks sharing c land on the same
// XCD (round-robin blk%8) so the 2MB c-slice stays hot in that XCD's L2.
__global__ __launch_bounds__(1024, 4) void fused_kernel(
    const float* __restrict__ x,        // [B][R][IN]
    const __half* __restrict__ vote_h,  // [C][R][O][IN]
    float* __restrict__ out)            // [B][C][O]
{
  const int blk = blockIdx.x;
  const int c = (blk & 7) * 4 + ((blk >> 3) >> 5);
  const int b = (blk >> 3) & 31;
  const int t = threadIdx.x;
  const int lane = t & 63;
  const int wave = t >> 6;

  __shared__ float red[16][32];
  __shared__ float verdict_s[32];
  __shared__ float scal[16];
  __shared__ float Ms, Zs;

  float v0[32], v1[32];

  // ---- compute votes row r = t ----
  {
    const uint4* wp = reinterpret_cast<const uint4*>(
        vote_h + ((size_t)c * R + t) * RO);
    const float4* xp = reinterpret_cast<const float4*>(
        x + ((size_t)b * R + t) * IN);
    float4 xa = xp[0], xb = xp[1], xc4 = xp[2], xd = xp[3];
#pragma unroll
    for (int o = 0; o < 32; ++o) {
      uint4 wa = wp[2 * o], wb = wp[2 * o + 1];
      const __half2* ha = reinterpret_cast<const __half2*>(&wa);
      const __half2* hb = reinterpret_cast<const __half2*>(&wb);
      float2 p0 = __half22float2(ha[0]), p1 = __half22float2(ha[1]);
      float2 p2 = __half22float2(ha[2]), p3 = __half22float2(ha[3]);
      float2 q0 = __half22float2(hb[0]), q1 = __half22float2(hb[1]);
      float2 q2 = __half22float2(hb[2]), q3 = __half22float2(hb[3]);
      v0[o] = p0.x * xa.x + p0.y * xa.y + p1.x * xa.z + p1.y * xa.w +
              p2.x * xb.x + p2.y * xb.y + p3.x * xb.z + p3.y * xb.w +
              q0.x * xc4.x + q0.y * xc4.y + q1.x * xc4.z + q1.y * xc4.w +
              q2.x * xd.x + q2.y * xd.y + q3.x * xd.z + q3.y * xd.w;
    }
  }
  // ---- compute votes row r = t + 1024 ----
  {
    const uint4* wp = reinterpret_cast<const uint4*>(
        vote_h + ((size_t)c * R + t + 1024) * RO);
    const float4* xp = reinterpret_cast<const float4*>(
        x + ((size_t)b * R + t + 1024) * IN);
    float4 xa = xp[0], xb = xp[1], xc4 = xp[2], xd = xp[3];
#pragma unroll
    for (int o = 0; o < 32; ++o) {
      uint4 wa = wp[2 * o], wb = wp[2 * o + 1];
      const __half2* ha = reinterpret_cast<const __half2*>(&wa);
      const __half2* hb = reinterpret_cast<const __half2*>(&wb);
      float2 p0 = __half22float2(ha[0]), p1 = __half22float2(ha[1]);
      float2 p2 = __half22float2(ha[2]), p3 = __half22float2(ha[3]);
      float2 q0 = __half22float2(hb[0]), q1 = __half22float2(hb[1]);
      float2 q2 = __half22float2(hb[2]), q3 = __half22float2(hb[3]);
      v1[o] = p0.x * xa.x + p0.y * xa.y + p1.x * xa.z + p1.y * xa.w +
              p2.x * xb.x + p2.y * xb.y + p3.x * xb.z + p3.y * xb.w +
              q0.x * xc4.x + q0.y * xc4.y + q1.x * xc4.z + q1.y * xc4.w +
              q2.x * xd.x + q2.y * xd.y + q3.x * xd.z + q3.y * xd.w;
    }
  }

  // ---- 3 routing iterations (verified structure from round 2) ----
  float a0 = 0.0f, a1 = 0.0f;

  for (int iter = 0; iter < 3; ++iter) {
    float m = fmaxf(a0, a1);
#pragma unroll
    for (int mask = 32; mask; mask >>= 1) m = fmaxf(m, __shfl_xor(m, mask));
    if (lane == 0) scal[wave] = m;
    __syncthreads();
    if (t == 0) {
      float mm = scal[0];
#pragma unroll
      for (int w = 1; w < 16; ++w) mm = fmaxf(mm, scal[w]);
      Ms = mm;
    }
    __syncthreads();
    const float M = Ms;

    float e0 = __expf(a0 - M), e1 = __expf(a1 - M);
    {
      float z = e0 + e1;
#pragma unroll
      for (int mask = 32; mask; mask >>= 1) z += __shfl_xor(z, mask);
      if (lane == 0) scal[wave] = z;
    }
    __syncthreads();
    if (t == 0) {
      float zz = 0.0f;
#pragma unroll
      for (int w = 0; w < 16; ++w) zz += scal[w];
      Zs = zz;
    }
    __syncthreads();
    const float Zinv = 1.0f / Zs;

    // S[o] in two 16-wide halves to limit register pressure.
    {
      float s[16];
#pragma unroll
      for (int o = 0; o < 16; ++o) s[o] = e0 * v0[o] + e1 * v1[o];
#pragma unroll
      for (int mask = 32; mask; mask >>= 1) {
#pragma unroll
        for (int o = 0; o < 16; ++o) s[o] += __shfl_xor(s[o], mask);
      }
#pragma unroll
      for (int o = 0; o < 16; ++o)
        if (lane == o) red[wave][o] = s[o];
    }
    {
      float s[16];
#pragma unroll
      for (int o = 0; o < 16; ++o) s[o] = e0 * v0[16 + o] + e1 * v1[16 + o];
#pragma unroll
      for (int mask = 32; mask; mask >>= 1) {
#pragma unroll
        for (int o = 0; o < 16; ++o) s[o] += __shfl_xor(s[o], mask);
      }
#pragma unroll
      for (int o = 0; o < 16; ++o)
        if (lane == 16 + o) red[wave][lane] = s[o];
    }
    __syncthreads();

    if (t < 32) {
      float S = 0.0f;
#pragma unroll
      for (int w = 0; w < 16; ++w) S += red[w][t];
      float summary = S * Zinv;
      float sq = summary * summary;
#pragma unroll
      for (int mask = 16; mask; mask >>= 1) sq += __shfl_xor(sq, mask);
      float scale = sq / ((1.0f + sq) * sqrtf(sq + 1e-8f));
      float vd = summary * scale;
      verdict_s[t] = vd;
      if (iter == 2) out[((size_t)b * C + c) * O + t] = vd;
    }
    __syncthreads();

    if (iter < 2) {
      float u0 = 0.0f, u1 = 0.0f;
#pragma unroll
      for (int o = 0; o < 32; ++o) {
        float vd = verdict_s[o];
        u0 += v0[o] * vd;
        u1 += v1[o] * vd;
      }
      a0 += u0;
      a1 += u1;
    }
    __syncthreads();
  }
}

extern "C" void kernel_launch(void* const* d_in, const int* in_sizes, int n_in,
                              void* d_out, int out_size, void* d_ws, size_t ws_size,
                              hipStream_t stream) {
  const float* x = (const float*)d_in[0];     // [32][2048][16]
  const float* vote = (const float*)d_in[1];  // [2048][32][32][16]
  float* out = (float*)d_out;                 // [32][32][32]
  __half* vote_h = (__half*)d_ws;             // [C][R][O][IN] fp16 = 64 MB

  convert_kernel<<<dim3((R * C * 64) / 256), 256, 0, stream>>>(vote, vote_h);
  fused_kernel<<<dim3(B * C), 1024, 0, stream>>>(x, vote_h, out);
}

// Round 4
// 436.773 us; speedup vs baseline: 6.7691x; 6.7691x over previous
//
#include <hip/hip_runtime.h>
#include <hip/hip_fp16.h>

#define B 32
#define R 2048
#define C 32
#define O 32
#define IN 16

// ---------------------------------------------------------------------------
// K1: votes_h[b][c][r][o] = (half) sum_i vote[r][c][o][i] * x[b][r][i]
// Block = (rchunk of 64 r, c), 512 threads: rl = t>>3 (0..63), oq = t&7.
// x slice staged fp16 in LDS (padded rows). vote read ONCE from HBM.
// ---------------------------------------------------------------------------
__global__ __launch_bounds__(512, 4) void votes_kernel(
    const float* __restrict__ x,     // [B][R][IN] fp32
    const float* __restrict__ vote,  // [R][C][O][IN] fp32
    __half* __restrict__ votes_h)    // [B][C][R][O] fp16
{
  const int r0 = blockIdx.x * 64;
  const int c = blockIdx.y;
  const int t = threadIdx.x;
  const int rl = t >> 3;   // 0..63
  const int oq = t & 7;    // o-quad: o = oq*4 .. oq*4+3
  const int r = r0 + rl;

  // x_lds[b][rl][q]: q<4 holds 4 halfs each (16 halfs = x[b][r][0..15]),
  // 5th uint2 is pad -> row stride 40 B (10 words) = conflict-free reads.
  __shared__ uint2 x_lds[32][64][5];  // 80 KB

  // ---- stage x (fp32 -> fp16), fully coalesced float4 reads ----
  // 8192 float4 total; 16 per thread.
#pragma unroll
  for (int k = 0; k < 16; ++k) {
    int j = t + k * 512;          // float4 index in slice
    int b = j >> 8;               // 256 float4 per b
    int rem = j & 255;
    int rr = rem >> 2;            // local r
    int ic = rem & 3;             // float4 within row
    float4 v = *reinterpret_cast<const float4*>(
        x + ((size_t)b * R + r0 + rr) * IN + ic * 4);
    __half2 h01 = __float22half2_rn(make_float2(v.x, v.y));
    __half2 h23 = __float22half2_rn(make_float2(v.z, v.w));
    uint2 pk;
    pk.x = __builtin_bit_cast(unsigned int, h01);
    pk.y = __builtin_bit_cast(unsigned int, h23);
    x_lds[b][rr][ic] = pk;
  }
  __syncthreads();

  // ---- load this thread's 4 vote rows (64 floats), read once ----
  const float4* vp = reinterpret_cast<const float4*>(
      vote + (((size_t)r * C + c) * O + oq * 4) * IN);
  float4 wv[16];
#pragma unroll
  for (int k = 0; k < 16; ++k) wv[k] = vp[k];

  // ---- loop over b: 4 dot-16 products per b, store half4 ----
  __half* outbase = votes_h + (size_t)c * R * O + (size_t)r * O + oq * 4;
#pragma unroll 4
  for (int b = 0; b < 32; ++b) {
    float xs[16];
#pragma unroll
    for (int q = 0; q < 4; ++q) {
      uint2 u = x_lds[b][rl][q];
      float2 f0 = __half22float2(__builtin_bit_cast(__half2, u.x));
      float2 f1 = __half22float2(__builtin_bit_cast(__half2, u.y));
      xs[4 * q + 0] = f0.x; xs[4 * q + 1] = f0.y;
      xs[4 * q + 2] = f1.x; xs[4 * q + 3] = f1.y;
    }
    float acc[4];
#pragma unroll
    for (int j = 0; j < 4; ++j) {
      float a = 0.0f;
#pragma unroll
      for (int k = 0; k < 4; ++k) {
        float4 w = wv[4 * j + k];
        a += w.x * xs[4 * k + 0] + w.y * xs[4 * k + 1] +
             w.z * xs[4 * k + 2] + w.w * xs[4 * k + 3];
      }
      acc[j] = a;
    }
    __half2 h01 = __float22half2_rn(make_float2(acc[0], acc[1]));
    __half2 h23 = __float22half2_rn(make_float2(acc[2], acc[3]));
    uint2 pk;
    pk.x = __builtin_bit_cast(unsigned int, h01);
    pk.y = __builtin_bit_cast(unsigned int, h23);
    // wave-contiguous 512B stores per b
    *reinterpret_cast<uint2*>(outbase + (size_t)b * C * R * O) = pk;
  }
}

// ---------------------------------------------------------------------------
// K2: one block per (b,c), 1024 threads. Votes slice staged in LDS
// (o4-plane layout: vplane[p][r] = halfs o=4p..4p+3 of row r; plane stride
// padded 2048->2056 to break p-collisions). Per-thread live state is tiny:
// a0,a1 + 16-float reduction chunks. No spill possible.
// ---------------------------------------------------------------------------
__global__ __launch_bounds__(1024) void routing_kernel(
    const __half* __restrict__ votes_h,  // [B][C][R][O]
    float* __restrict__ out)             // [B][C][O]
{
  const int b = blockIdx.x >> 5;
  const int c = blockIdx.x & 31;
  const int t = threadIdx.x;
  const int lane = t & 63;
  const int wave = t >> 6;  // 0..15

  __shared__ uint2 vplane[8][2056];  // 131584 B
  __shared__ float red[16][32];
  __shared__ float verdict_s[32];
  __shared__ float scal[16];
  __shared__ float Ms, Zs;

  // ---- stage votes slice: 128 KB, uint4-coalesced ----
  const uint4* src = reinterpret_cast<const uint4*>(
      votes_h + ((size_t)b * C + c) * R * O);
#pragma unroll
  for (int k = 0; k < 8; ++k) {
    int j = t + k * 1024;     // 16B chunk index; 8192 total
    uint4 v = src[j];
    int r = j >> 2;           // 4 chunks per row
    int p = (j & 3) * 2;      // two o4-groups per chunk
    uint2 a; a.x = v.x; a.y = v.y;
    uint2 d; d.x = v.z; d.y = v.w;
    vplane[p][r] = a;
    vplane[p + 1][r] = d;
  }
  __syncthreads();

  const int rA = t;           // owned rows
  const int rB = t + 1024;

  float a0 = 0.0f, a1 = 0.0f;

  for (int iter = 0; iter < 3; ++iter) {
    // ---- block max of agreement ----
    float m = fmaxf(a0, a1);
#pragma unroll
    for (int mask = 32; mask; mask >>= 1) m = fmaxf(m, __shfl_xor(m, mask));
    if (lane == 0) scal[wave] = m;
    __syncthreads();
    if (t == 0) {
      float mm = scal[0];
#pragma unroll
      for (int w = 1; w < 16; ++w) mm = fmaxf(mm, scal[w]);
      Ms = mm;
    }
    __syncthreads();
    const float M = Ms;

    // ---- exp + block sum ----
    float e0 = __expf(a0 - M), e1 = __expf(a1 - M);
    {
      float z = e0 + e1;
#pragma unroll
      for (int mask = 32; mask; mask >>= 1) z += __shfl_xor(z, mask);
      if (lane == 0) scal[wave] = z;
    }
    __syncthreads();
    if (t == 0) {
      float zz = 0.0f;
#pragma unroll
      for (int w = 0; w < 16; ++w) zz += scal[w];
      Zs = zz;
    }
    __syncthreads();
    const float Zinv = 1.0f / Zs;

    // ---- S[o] = sum_r e[r]*v[r][o], two 16-wide halves from LDS ----
    {
      float s[16];
#pragma unroll
      for (int q = 0; q < 4; ++q) {  // o = 4q..4q+3
        uint2 uA = vplane[q][rA];
        uint2 uB = vplane[q][rB];
        float2 A0 = __half22float2(__builtin_bit_cast(__half2, uA.x));
        float2 A1 = __half22float2(__builtin_bit_cast(__half2, uA.y));
        float2 B0 = __half22float2(__builtin_bit_cast(__half2, uB.x));
        float2 B1 = __half22float2(__builtin_bit_cast(__half2, uB.y));
        s[4 * q + 0] = e0 * A0.x + e1 * B0.x;
        s[4 * q + 1] = e0 * A0.y + e1 * B0.y;
        s[4 * q + 2] = e0 * A1.x + e1 * B1.x;
        s[4 * q + 3] = e0 * A1.y + e1 * B1.y;
      }
#pragma unroll
      for (int mask = 32; mask; mask >>= 1) {
#pragma unroll
        for (int o = 0; o < 16; ++o) s[o] += __shfl_xor(s[o], mask);
      }
#pragma unroll
      for (int o = 0; o < 16; ++o)
        if (lane == o) red[wave][o] = s[o];  // lanes 0..15
    }
    {
      float s[16];
#pragma unroll
      for (int q = 4; q < 8; ++q) {  // o = 16 + ...
        uint2 uA = vplane[q][rA];
        uint2 uB = vplane[q][rB];
        float2 A0 = __half22float2(__builtin_bit_cast(__half2, uA.x));
        float2 A1 = __half22float2(__builtin_bit_cast(__half2, uA.y));
        float2 B0 = __half22float2(__builtin_bit_cast(__half2, uB.x));
        float2 B1 = __half22float2(__builtin_bit_cast(__half2, uB.y));
        int oo = 4 * (q - 4);
        s[oo + 0] = e0 * A0.x + e1 * B0.x;
        s[oo + 1] = e0 * A0.y + e1 * B0.y;
        s[oo + 2] = e0 * A1.x + e1 * B1.x;
        s[oo + 3] = e0 * A1.y + e1 * B1.y;
      }
#pragma unroll
      for (int mask = 32; mask; mask >>= 1) {
#pragma unroll
        for (int o = 0; o < 16; ++o) s[o] += __shfl_xor(s[o], mask);
      }
#pragma unroll
      for (int o = 0; o < 16; ++o)
        if (lane == 16 + o) red[wave][lane] = s[o];  // lanes 16..31
    }
    __syncthreads();

    // ---- wave 0: finish reduction, squash, verdict ----
    if (t < 32) {
      float S = 0.0f;
#pragma unroll
      for (int w = 0; w < 16; ++w) S += red[w][t];
      float summary = S * Zinv;
      float sq = summary * summary;
#pragma unroll
      for (int mask = 16; mask; mask >>= 1) sq += __shfl_xor(sq, mask);
      float scale = sq / ((1.0f + sq) * sqrtf(sq + 1e-8f));
      float vd = summary * scale;
      verdict_s[t] = vd;
      if (iter == 2) out[((size_t)b * C + c) * O + t] = vd;
    }
    __syncthreads();

    // ---- agreement update (skipped on last iter) ----
    if (iter < 2) {
      float u0 = 0.0f, u1 = 0.0f;
#pragma unroll
      for (int q = 0; q < 8; ++q) {
        uint2 uA = vplane[q][rA];
        uint2 uB = vplane[q][rB];
        float2 A0 = __half22float2(__builtin_bit_cast(__half2, uA.x));
        float2 A1 = __half22float2(__builtin_bit_cast(__half2, uA.y));
        float2 B0 = __half22float2(__builtin_bit_cast(__half2, uB.x));
        float2 B1 = __half22float2(__builtin_bit_cast(__half2, uB.y));
        float vd0 = verdict_s[4 * q + 0];
        float vd1 = verdict_s[4 * q + 1];
        float vd2 = verdict_s[4 * q + 2];
        float vd3 = verdict_s[4 * q + 3];
        u0 += A0.x * vd0 + A0.y * vd1 + A1.x * vd2 + A1.y * vd3;
        u1 += B0.x * vd0 + B0.y * vd1 + B1.x * vd2 + B1.y * vd3;
      }
      a0 += u0;
      a1 += u1;
      __syncthreads();
    }
  }
}

extern "C" void kernel_launch(void* const* d_in, const int* in_sizes, int n_in,
                              void* d_out, int out_size, void* d_ws, size_t ws_size,
                              hipStream_t stream) {
  const float* x = (const float*)d_in[0];     // [32][2048][16]
  const float* vote = (const float*)d_in[1];  // [2048][32][32][16]
  float* out = (float*)d_out;                 // [32][32][32]
  __half* votes_h = (__half*)d_ws;            // [B][C][R][O] fp16 = 128 MB

  votes_kernel<<<dim3(R / 64, C), 512, 0, stream>>>(x, vote, votes_h);
  routing_kernel<<<dim3(B * C), 1024, 0, stream>>>(votes_h, out);
}

// Round 5
// 284.298 us; speedup vs baseline: 10.3995x; 1.5363x over previous
//
#include <hip/hip_runtime.h>
#include <hip/hip_fp16.h>

#define B 32
#define R 2048
#define C 32
#define O 32
#define IN 16

// votes_h layout: per (b,c) slice of 65536 halfs, element (rp, o, parity) at
// rp*64 + o*2 + parity, i.e. half2(row 2rp, row 2rp+1) per o — directly
// LDS-stageable by K2.

// ---------------------------------------------------------------------------
// K1: thread = (rl 0..15, o 0..31), 512 threads; block = (16-row chunk, c).
// vote row kept in 16 fp32 registers (no spill), x staged fp16 in LDS.
// ---------------------------------------------------------------------------
__global__ __launch_bounds__(512) void votes_kernel(
    const float* __restrict__ x,     // [B][R][IN] fp32
    const float* __restrict__ vote,  // [R][C][O][IN] fp32
    __half* __restrict__ votes_h)    // interleaved, see above
{
  const int r0 = blockIdx.x * 16;
  const int c = blockIdx.y;
  const int t = threadIdx.x;
  const int o = t & 31;
  const int rl = t >> 5;  // 0..15
  const int r = r0 + rl;

  // x_lds row = 16 halfs (8 words) at stride 12 words (16B-aligned b128 reads)
  __shared__ unsigned int x_lds[32 * 16 * 12];  // 24 KB

  // ---- stage x fp32 -> fp16 (2048 float4, 4 per thread, coalesced) ----
#pragma unroll
  for (int k = 0; k < 4; ++k) {
    int j = t + k * 512;
    int bb = j >> 6;
    int rr = (j >> 2) & 15;
    int ic = j & 3;
    float4 v = *reinterpret_cast<const float4*>(
        x + ((size_t)bb * R + r0 + rr) * IN + ic * 4);
    __half2 h01 = __float22half2_rn(make_float2(v.x, v.y));
    __half2 h23 = __float22half2_rn(make_float2(v.z, v.w));
    int w = (bb * 16 + rr) * 12 + 2 * ic;
    x_lds[w] = __builtin_bit_cast(unsigned int, h01);
    x_lds[w + 1] = __builtin_bit_cast(unsigned int, h23);
  }
  __syncthreads();

  // ---- vote row (r,c,o,0..15): 16 fp32 regs, read once ----
  const float4* vp = reinterpret_cast<const float4*>(
      vote + (((size_t)r * C + c) * O + o) * IN);
  float4 f0 = vp[0], f1 = vp[1], f2 = vp[2], f3 = vp[3];

  // output address: interleaved row-pair layout
  __half* optr = votes_h + (size_t)c * 65536 +
                 (size_t)(r >> 1) * 64 + o * 2 + (r & 1);

#pragma unroll 2
  for (int bb = 0; bb < 32; ++bb) {
    const unsigned int* xr = &x_lds[(bb * 16 + rl) * 12];
    uint4 xa = *reinterpret_cast<const uint4*>(xr);      // halfs 0..7
    uint4 xb = *reinterpret_cast<const uint4*>(xr + 4);  // halfs 8..15
    __half2 h0 = __builtin_bit_cast(__half2, xa.x);
    __half2 h1 = __builtin_bit_cast(__half2, xa.y);
    __half2 h2 = __builtin_bit_cast(__half2, xa.z);
    __half2 h3 = __builtin_bit_cast(__half2, xa.w);
    __half2 h4 = __builtin_bit_cast(__half2, xb.x);
    __half2 h5 = __builtin_bit_cast(__half2, xb.y);
    __half2 h6 = __builtin_bit_cast(__half2, xb.z);
    __half2 h7 = __builtin_bit_cast(__half2, xb.w);
    float acc =
        f0.x * __low2float(h0) + f0.y * __high2float(h0) +
        f0.z * __low2float(h1) + f0.w * __high2float(h1) +
        f1.x * __low2float(h2) + f1.y * __high2float(h2) +
        f1.z * __low2float(h3) + f1.w * __high2float(h3) +
        f2.x * __low2float(h4) + f2.y * __high2float(h4) +
        f2.z * __low2float(h5) + f2.w * __high2float(h5) +
        f3.x * __low2float(h6) + f3.y * __high2float(h6) +
        f3.z * __low2float(h7) + f3.w * __high2float(h7);
    optr[(size_t)bb * C * 65536] = __float2half(acc);
  }
}

// ---------------------------------------------------------------------------
// K2: one block per (b,c), 1024 threads. vmix[rp][o] = half2(v[2rp][o],
// v[2rp+1][o]) at word rp*34+o (stride-34 pad). Thread t owns rows 2t,2t+1.
// S-reduction via (g,o) remap (no big shuffle trees).
// ---------------------------------------------------------------------------
__global__ __launch_bounds__(1024, 4) void routing_kernel(
    const __half* __restrict__ votes_h,
    float* __restrict__ out)  // [B][C][O]
{
  const int b = blockIdx.x >> 5;
  const int c = blockIdx.x & 31;
  const int t = threadIdx.x;
  const int lane = t & 63;
  const int wave = t >> 6;  // 0..15
  const int g = t >> 5;     // 0..31
  const int o = t & 31;

  __shared__ unsigned int vmix[1024 * 34];  // 139264 B
  __shared__ float2 e2[1024];               // 8 KB
  __shared__ float red[32][33];             // 4224 B
  __shared__ float vdf[32];
  __shared__ float scal_m[16], scal_z[16];

  // ---- stage votes slice (128 KB): uint4 global -> 2x uint2 LDS ----
  const uint4* src = reinterpret_cast<const uint4*>(
      votes_h + ((size_t)b * C + c) * 65536);
#pragma unroll
  for (int k = 0; k < 8; ++k) {
    int j = t + k * 1024;        // 16B chunk; 8 chunks per rp
    uint4 v = src[j];
    int rp = j >> 3;
    int q = j & 7;               // covers o = 4q .. 4q+3
    unsigned int* dst = &vmix[rp * 34 + 4 * q];
    uint2 a; a.x = v.x; a.y = v.y;
    uint2 d; d.x = v.z; d.y = v.w;
    *reinterpret_cast<uint2*>(dst) = a;
    *reinterpret_cast<uint2*>(dst + 2) = d;
  }
  __syncthreads();

  float a0 = 0.0f, a1 = 0.0f;

  for (int iter = 0; iter < 3; ++iter) {
    // ---- block max of agreement: wave shuffle + redundant final ----
    float m = fmaxf(a0, a1);
#pragma unroll
    for (int mask = 32; mask; mask >>= 1) m = fmaxf(m, __shfl_xor(m, mask));
    if (lane == 0) scal_m[wave] = m;
    __syncthreads();
    float M = scal_m[0];
#pragma unroll
    for (int w = 1; w < 16; ++w) M = fmaxf(M, scal_m[w]);

    // ---- exp; wave-sum; write e2 ----
    float e0 = __expf(a0 - M), e1 = __expf(a1 - M);
    {
      float z = e0 + e1;
#pragma unroll
      for (int mask = 32; mask; mask >>= 1) z += __shfl_xor(z, mask);
      if (lane == 0) scal_z[wave] = z;
    }
    e2[t] = make_float2(e0, e1);
    __syncthreads();
    float Z = 0.0f;
#pragma unroll
    for (int w = 0; w < 16; ++w) Z += scal_z[w];
    const float Zinv = 1.0f / Z;

    // ---- S partials: thread (g,o) sums 32 row-pairs ----
    {
      float s = 0.0f;
      const unsigned int* vb = &vmix[(size_t)g * 32 * 34 + o];
      const float2* eb = &e2[g * 32];
#pragma unroll
      for (int j = 0; j < 32; ++j) {
        __half2 vv = __builtin_bit_cast(__half2, vb[j * 34]);
        float2 ee = eb[j];
        s += ee.x * __low2float(vv) + ee.y * __high2float(vv);
      }
      red[o][g] = s;
    }
    __syncthreads();

    // ---- wave 0: finish S, squash, publish verdict ----
    if (t < 32) {
      float S = 0.0f;
#pragma unroll
      for (int gg = 0; gg < 32; ++gg) S += red[t][gg];
      float summary = S * Zinv;
      float sq = summary * summary;
#pragma unroll
      for (int mask = 16; mask; mask >>= 1) sq += __shfl_xor(sq, mask);
      float scale = sq / ((1.0f + sq) * sqrtf(sq + 1e-8f));
      float vd = summary * scale;
      vdf[t] = vd;
      if (iter == 2) out[((size_t)b * C + c) * O + t] = vd;
    }
    __syncthreads();

    // ---- agreement update (dead on last iter) ----
    if (iter < 2) {
      float u0 = 0.0f, u1 = 0.0f;
      const unsigned int* vb = &vmix[(size_t)t * 34];
#pragma unroll
      for (int q = 0; q < 16; ++q) {
        uint2 vv = *reinterpret_cast<const uint2*>(vb + 2 * q);
        __half2 va = __builtin_bit_cast(__half2, vv.x);  // o = 2q
        __half2 vbh = __builtin_bit_cast(__half2, vv.y); // o = 2q+1
        float vda = vdf[2 * q], vdb = vdf[2 * q + 1];
        u0 += __low2float(va) * vda + __low2float(vbh) * vdb;
        u1 += __high2float(va) * vda + __high2float(vbh) * vdb;
      }
      a0 += u0;
      a1 += u1;
      __syncthreads();
    }
  }
}

extern "C" void kernel_launch(void* const* d_in, const int* in_sizes, int n_in,
                              void* d_out, int out_size, void* d_ws, size_t ws_size,
                              hipStream_t stream) {
  const float* x = (const float*)d_in[0];     // [32][2048][16]
  const float* vote = (const float*)d_in[1];  // [2048][32][32][16]
  float* out = (float*)d_out;                 // [32][32][32]
  __half* votes_h = (__half*)d_ws;            // 128 MB interleaved

  votes_kernel<<<dim3(R / 16, C), 512, 0, stream>>>(x, vote, votes_h);
  routing_kernel<<<dim3(B * C), 1024, 0, stream>>>(votes_h, out);
}

// Round 6
// 283.954 us; speedup vs baseline: 10.4121x; 1.0012x over previous
//
#include <hip/hip_runtime.h>
#include <hip/hip_fp16.h>

#define B 32
#define R 2048
#define C 32
#define O 32
#define IN 16

typedef _Float16 hf2 __attribute__((ext_vector_type(2)));

// votes_h layout: per (b,c) slice of 65536 halfs; word index rp*32+o holds
// half2(v[2rp][o], v[2rp+1][o]).

// ---------------------------------------------------------------------------
// K1: block = (32-row chunk, c-pair), 512 threads:
//   c = blockIdx.y*2 + (t>>8); rp_l = (t>>4)&15; op = t&15  (o = 2op, 2op+1)
// Thread computes rows (r, r+1) x o-pair = 4 dots per bb via v_dot2_f32_f16.
// Vote rows live in 32 packed-half2 regs (converted once). x staged fp16 LDS.
// ---------------------------------------------------------------------------
__global__ __launch_bounds__(512, 4) void votes_kernel(
    const float* __restrict__ x,     // [B][R][IN] fp32
    const float* __restrict__ vote,  // [R][C][O][IN] fp32
    __half* __restrict__ votes_h)
{
  const int t = threadIdx.x;
  const int c = blockIdx.y * 2 + (t >> 8);
  const int tt = t & 255;
  const int rp_l = tt >> 4;                  // 0..15
  const int op = tt & 15;                    // o-pair
  const int r0 = blockIdx.x * 32;
  const int r = r0 + 2 * rp_l;
  const int rpg = blockIdx.x * 16 + rp_l;    // global row-pair

  __shared__ unsigned int x_lds[32 * 32 * 8];  // [bb][rl][8 words], 32 KB

  // ---- stage x fp32 -> fp16 (4096 float4, 8 per thread, coalesced) ----
#pragma unroll
  for (int k = 0; k < 8; ++k) {
    int j = t + k * 512;
    int bb = j >> 7;
    int rr = (j >> 2) & 31;
    int ic = j & 3;
    float4 v = *reinterpret_cast<const float4*>(
        x + ((size_t)bb * R + r0 + rr) * IN + ic * 4);
    __half2 h01 = __float22half2_rn(make_float2(v.x, v.y));
    __half2 h23 = __float22half2_rn(make_float2(v.z, v.w));
    int w = (bb * 32 + rr) * 8 + 2 * ic;
    x_lds[w] = __builtin_bit_cast(unsigned int, h01);
    x_lds[w + 1] = __builtin_bit_cast(unsigned int, h23);
  }

  // ---- load + convert 4 vote rows (rows r,r+1 x o=2op,2op+1) ----
  // wh[p*2+q][k]: row parity p, o parity q, 8 half2 along i.
  unsigned int wh[4][8];
#pragma unroll
  for (int p = 0; p < 2; ++p) {
#pragma unroll
    for (int q = 0; q < 2; ++q) {
      const float4* vp = reinterpret_cast<const float4*>(
          vote + (((size_t)(r + p) * C + c) * O + 2 * op + q) * IN);
#pragma unroll
      for (int k = 0; k < 4; ++k) {
        float4 f = vp[k];
        __half2 a = __float22half2_rn(make_float2(f.x, f.y));
        __half2 d = __float22half2_rn(make_float2(f.z, f.w));
        wh[p * 2 + q][2 * k] = __builtin_bit_cast(unsigned int, a);
        wh[p * 2 + q][2 * k + 1] = __builtin_bit_cast(unsigned int, d);
      }
    }
  }
  __syncthreads();

  // output base for bb=0
  __half* ob = votes_h + (size_t)c * 65536 + (size_t)rpg * 64 + op * 4;

#pragma unroll 2
  for (int bb = 0; bb < 32; ++bb) {
    const uint4* xr = reinterpret_cast<const uint4*>(
        &x_lds[(bb * 32 + 2 * rp_l) * 8]);
    uint4 xa = xr[0], xb = xr[1];  // row r   (8 half2)
    uint4 xc = xr[2], xd = xr[3];  // row r+1 (8 half2)
    unsigned int x0[8] = {xa.x, xa.y, xa.z, xa.w, xb.x, xb.y, xb.z, xb.w};
    unsigned int x1[8] = {xc.x, xc.y, xc.z, xc.w, xd.x, xd.y, xd.z, xd.w};
    float a00 = 0.f, a01 = 0.f, a10 = 0.f, a11 = 0.f;
#pragma unroll
    for (int k = 0; k < 8; ++k) {
      hf2 xv0 = __builtin_bit_cast(hf2, x0[k]);
      hf2 xv1 = __builtin_bit_cast(hf2, x1[k]);
      a00 = __builtin_amdgcn_fdot2(__builtin_bit_cast(hf2, wh[0][k]), xv0, a00, false);
      a01 = __builtin_amdgcn_fdot2(__builtin_bit_cast(hf2, wh[1][k]), xv0, a01, false);
      a10 = __builtin_amdgcn_fdot2(__builtin_bit_cast(hf2, wh[2][k]), xv1, a10, false);
      a11 = __builtin_amdgcn_fdot2(__builtin_bit_cast(hf2, wh[3][k]), xv1, a11, false);
    }
    // word o=2op: half2(row r, row r+1); word o=2op+1 likewise
    __half2 w0 = __float22half2_rn(make_float2(a00, a10));
    __half2 w1 = __float22half2_rn(make_float2(a01, a11));
    uint2 pk;
    pk.x = __builtin_bit_cast(unsigned int, w0);
    pk.y = __builtin_bit_cast(unsigned int, w1);
    *reinterpret_cast<uint2*>(ob + (size_t)bb * C * 65536) = pk;
  }
}

// ---------------------------------------------------------------------------
// K2: one block per (b,c), 1024 threads. vmix[rp][o] = half2(v[2rp][o],
// v[2rp+1][o]) at word rp*34+o. No max-subtraction (|a| small, exp fits
// fp32); iter-0 fast path (e==1, Z=2048, no e2 staging).
// ---------------------------------------------------------------------------
__global__ __launch_bounds__(1024, 4) void routing_kernel(
    const __half* __restrict__ votes_h,
    float* __restrict__ out)  // [B][C][O]
{
  const int b = blockIdx.x >> 5;
  const int c = blockIdx.x & 31;
  const int t = threadIdx.x;
  const int lane = t & 63;
  const int wave = t >> 6;  // 0..15
  const int g = t >> 5;     // 0..31
  const int o = t & 31;

  __shared__ unsigned int vmix[1024 * 34];  // 139264 B
  __shared__ float2 e2[1024];               // 8 KB
  __shared__ float red[32][33];
  __shared__ float vdf[32];
  __shared__ float scal_z[16];

  // ---- stage votes slice (128 KB) ----
  const uint4* src = reinterpret_cast<const uint4*>(
      votes_h + ((size_t)b * C + c) * 65536);
#pragma unroll
  for (int k = 0; k < 8; ++k) {
    int j = t + k * 1024;
    uint4 v = src[j];
    int rp = j >> 3;
    int q = j & 7;
    unsigned int* dst = &vmix[rp * 34 + 4 * q];
    uint2 a; a.x = v.x; a.y = v.y;
    uint2 d; d.x = v.z; d.y = v.w;
    *reinterpret_cast<uint2*>(dst) = a;
    *reinterpret_cast<uint2*>(dst + 2) = d;
  }
  __syncthreads();

  float a0 = 0.0f, a1 = 0.0f;
  float Zinv = 1.0f / 2048.0f;

  for (int iter = 0; iter < 3; ++iter) {
    if (iter > 0) {
      float e0 = __expf(a0), e1 = __expf(a1);
      float z = e0 + e1;
#pragma unroll
      for (int mask = 32; mask; mask >>= 1) z += __shfl_xor(z, mask);
      if (lane == 0) scal_z[wave] = z;
      e2[t] = make_float2(e0, e1);
      __syncthreads();
      float Z = 0.0f;
#pragma unroll
      for (int w = 0; w < 16; ++w) Z += scal_z[w];
      Zinv = 1.0f / Z;
    }

    // ---- S partials: thread (g,o) sums 32 row-pairs ----
    {
      float s = 0.0f;
      const unsigned int* vb = &vmix[(size_t)g * 32 * 34 + o];
      if (iter == 0) {
#pragma unroll
        for (int j = 0; j < 32; ++j) {
          __half2 vv = __builtin_bit_cast(__half2, vb[j * 34]);
          s += __low2float(vv) + __high2float(vv);
        }
      } else {
        const float2* eb = &e2[g * 32];
#pragma unroll
        for (int j = 0; j < 32; ++j) {
          __half2 vv = __builtin_bit_cast(__half2, vb[j * 34]);
          float2 ee = eb[j];
          s += ee.x * __low2float(vv) + ee.y * __high2float(vv);
        }
      }
      red[o][g] = s;
    }
    __syncthreads();

    // ---- wave 0: finish S, squash, publish verdict ----
    if (t < 32) {
      float S = 0.0f;
#pragma unroll
      for (int gg = 0; gg < 32; ++gg) S += red[t][gg];
      float summary = S * Zinv;
      float sq = summary * summary;
#pragma unroll
      for (int mask = 16; mask; mask >>= 1) sq += __shfl_xor(sq, mask);
      float scale = sq / ((1.0f + sq) * sqrtf(sq + 1e-8f));
      float vd = summary * scale;
      vdf[t] = vd;
      if (iter == 2) out[((size_t)b * C + c) * O + t] = vd;
    }
    __syncthreads();

    // ---- agreement update (dead on last iter) ----
    if (iter < 2) {
      float u0 = 0.0f, u1 = 0.0f;
      const unsigned int* vb = &vmix[(size_t)t * 34];
#pragma unroll
      for (int q = 0; q < 16; ++q) {
        uint2 vv = *reinterpret_cast<const uint2*>(vb + 2 * q);
        __half2 va = __builtin_bit_cast(__half2, vv.x);   // o = 2q
        __half2 vbh = __builtin_bit_cast(__half2, vv.y);  // o = 2q+1
        float vda = vdf[2 * q], vdb = vdf[2 * q + 1];
        u0 += __low2float(va) * vda + __low2float(vbh) * vdb;
        u1 += __high2float(va) * vda + __high2float(vbh) * vdb;
      }
      a0 += u0;
      a1 += u1;
    }
  }
}

extern "C" void kernel_launch(void* const* d_in, const int* in_sizes, int n_in,
                              void* d_out, int out_size, void* d_ws, size_t ws_size,
                              hipStream_t stream) {
  const float* x = (const float*)d_in[0];     // [32][2048][16]
  const float* vote = (const float*)d_in[1];  // [2048][32][32][16]
  float* out = (float*)d_out;                 // [32][32][32]
  __half* votes_h = (__half*)d_ws;            // 134 MB interleaved

  votes_kernel<<<dim3(R / 32, C / 2), 512, 0, stream>>>(x, vote, votes_h);
  routing_kernel<<<dim3(B * C), 1024, 0, stream>>>(votes_h, out);
}